// Round 13
// baseline (2636.971 us; speedup 1.0000x reference)
//
#include <hip/hip_runtime.h>
#include <cstdint>
#include <cstddef>

#define BB 128   // batch
#define EE 512   // input dim
#define HH 1024  // hidden
#define G4 4096
#define OO 512   // output dim
#define NBLKP 128    // persistent grid: 128 blocks (residency ceiling; 256 failed r9)
#define NTHR 512     // 8 waves: 4 gates (32 rows) + 4 FC (concurrent)
#define RED36 36     // reduce-buffer row stride (floats)
#define SMEM_BYTES (131072 + BB * RED36 * 4 + 4096)  // W hi+lo + red + fred
#define SPIN_LIMIT (1u << 16)  // bounded spin: deadlock -> wrong answer, not hang
#define FLAGSTRIDE 16          // flags spaced 64B apart

typedef float f32x4 __attribute__((ext_vector_type(4)));
typedef short s16x8 __attribute__((ext_vector_type(8)));
typedef __bf16 b16x8 __attribute__((ext_vector_type(8)));

// ---- mfma dispatch: tolerate either short8- or bf16x8-typed builtin ----
template <typename V>
__device__ __forceinline__ auto mfma_try(V a, V b, f32x4 c, int)
    -> decltype(__builtin_amdgcn_mfma_f32_16x16x32_bf16(a, b, c, 0, 0, 0)) {
  return __builtin_amdgcn_mfma_f32_16x16x32_bf16(a, b, c, 0, 0, 0);
}
template <typename V>
__device__ __forceinline__ f32x4 mfma_try(V a, V b, f32x4 c, long) {
  b16x8 ab = __builtin_bit_cast(b16x8, a);
  b16x8 bb = __builtin_bit_cast(b16x8, b);
  return __builtin_amdgcn_mfma_f32_16x16x32_bf16(ab, bb, c, 0, 0, 0);
}
__device__ __forceinline__ f32x4 mfma_bf16(s16x8 a, s16x8 b, f32x4 c) {
  return mfma_try(a, b, c, 0);
}

__device__ __forceinline__ float bf2f(ushort s) {
  unsigned int u = ((unsigned int)s) << 16;
  return __builtin_bit_cast(float, u);
}
__device__ __forceinline__ ushort f2bf(float f) {
  unsigned int u = __builtin_bit_cast(unsigned int, f);
  unsigned int r = (u + 0x7fffu + ((u >> 16) & 1u)) >> 16;
  return (ushort)r;
}
__device__ __forceinline__ float sigm(float x) {
  return 1.0f / (1.0f + __expf(-x));
}
// write-through agent-scope 16-bit store (block-major h => full 64B lines)
__device__ __forceinline__ void store_short_agent(ushort* p, ushort v) {
  asm volatile("global_store_short %0, %1, off sc1"
               :: "v"(p), "v"((unsigned)v) : "memory");
}

// ======== fp32 -> split bf16 (hi+lo) for x, W_ih, W_hh, fc_w ============
__global__ void __launch_bounds__(256)
convert_split(const float* __restrict__ x, const float* __restrict__ Wih,
              const float* __restrict__ Whh, const float* __restrict__ fcw,
              ushort* __restrict__ xh, ushort* __restrict__ xl,
              ushort* __restrict__ Wihh, ushort* __restrict__ Wihl,
              ushort* __restrict__ Whhh, ushort* __restrict__ Whhl,
              ushort* __restrict__ fcwh, ushort* __restrict__ fcwl,
              unsigned* __restrict__ flags) {
  if (blockIdx.x == 0) {
    for (int j = threadIdx.x; j < NBLKP * FLAGSTRIDE; j += 256) flags[j] = 0u;
  }
  const long n0 = (long)BB * EE;
  const long n1 = n0 + (long)G4 * EE;
  const long n2 = n1 + (long)G4 * HH;
  long i = ((long)blockIdx.x * 256 + threadIdx.x) * 4;
  const float* src;
  ushort *dh, *dl;
  long off;
  if (i < n0) {
    src = x; dh = xh; dl = xl; off = i;
  } else if (i < n1) {
    src = Wih; dh = Wihh; dl = Wihl; off = i - n0;
  } else if (i < n2) {
    src = Whh; dh = Whhh; dl = Whhl; off = i - n1;
  } else {
    src = fcw; dh = fcwh; dl = fcwl; off = i - n2;
  }
  float4 v = *(const float4*)&src[off];
  ushort4 h;
  h.x = f2bf(v.x); h.y = f2bf(v.y); h.z = f2bf(v.z); h.w = f2bf(v.w);
  *(ushort4*)&dh[off] = h;
  ushort4 l;
  l.x = f2bf(v.x - bf2f(h.x));
  l.y = f2bf(v.y - bf2f(h.y));
  l.z = f2bf(v.z - bf2f(h.z));
  l.w = f2bf(v.w - bf2f(h.w));
  *(ushort4*)&dl[off] = l;
}

// ========== z = x @ W_ih^T + (b_ih+b_hh) -> zbuf fp32 [B][4H] ===========
__global__ void __launch_bounds__(256)
z_split(const ushort* __restrict__ xh, const ushort* __restrict__ xl,
        const ushort* __restrict__ Wihh, const ushort* __restrict__ Wihl,
        const float* __restrict__ bih, const float* __restrict__ bhh,
        float* __restrict__ zbuf) {
  __shared__ alignas(16) ushort Ah[64][72];
  __shared__ alignas(16) ushort Al[64][72];
  __shared__ alignas(16) ushort Bh[32][72];
  __shared__ alignas(16) ushort Bl[32][72];
  const int tid = threadIdx.x, bid = blockIdx.x;
  const int m0 = (bid >> 7) * 64;
  const int hbase = (bid & 127) * 8;
  const int lane = tid & 63, wave = tid >> 6;
  const int wm = wave & 1, wn = wave >> 1;
  const int fr_row = lane & 15, fr_k = (lane >> 4) * 8;
  const f32x4 fz = {0.f, 0.f, 0.f, 0.f};

  f32x4 a0 = fz, a1 = fz;
  for (int kt = 0; kt < EE / 64; ++kt) {
    for (int i = 0; i < 2; ++i) {
      int idx = tid + i * 256;
      int r = idx >> 3, c8 = (idx & 7) * 8;
      int go = (m0 + r) * EE + kt * 64 + c8;
      *(uint4*)&Ah[r][c8] = *(const uint4*)&xh[go];
      *(uint4*)&Al[r][c8] = *(const uint4*)&xl[go];
    }
    {
      int r = tid >> 3, c8 = (tid & 7) * 8;
      int wrow = (r >> 3) * HH + hbase + (r & 7);
      int go = wrow * EE + kt * 64 + c8;
      *(uint4*)&Bh[r][c8] = *(const uint4*)&Wihh[go];
      *(uint4*)&Bl[r][c8] = *(const uint4*)&Wihl[go];
    }
    __syncthreads();
    for (int kc = 0; kc < 2; ++kc) {
      int ko = kc * 32 + fr_k;
      s16x8 bh = *(const s16x8*)&Bh[wn * 16 + fr_row][ko];
      s16x8 bl = *(const s16x8*)&Bl[wn * 16 + fr_row][ko];
      s16x8 f0h = *(const s16x8*)&Ah[wm * 32 + fr_row][ko];
      s16x8 f0l = *(const s16x8*)&Al[wm * 32 + fr_row][ko];
      s16x8 f1h = *(const s16x8*)&Ah[wm * 32 + 16 + fr_row][ko];
      s16x8 f1l = *(const s16x8*)&Al[wm * 32 + 16 + fr_row][ko];
      a0 = mfma_bf16(f0h, bh, a0);
      a0 = mfma_bf16(f0l, bh, a0);
      a0 = mfma_bf16(f0h, bl, a0);
      a1 = mfma_bf16(f1h, bh, a1);
      a1 = mfma_bf16(f1l, bh, a1);
      a1 = mfma_bf16(f1h, bl, a1);
    }
    __syncthreads();
  }
  int jcol = wn * 16 + fr_row;
  int gc = (jcol >> 3) * HH + hbase + (jcol & 7);
  float bias = bih[gc] + bhh[gc];
  int rbase = wm * 32 + (lane >> 4) * 4;
#pragma unroll
  for (int r = 0; r < 4; ++r) {
    zbuf[(size_t)(m0 + rbase + r) * G4 + gc] = a0[r] + bias;
    zbuf[(size_t)(m0 + rbase + 16 + r) * G4 + gc] = a1[r] + bias;
  }
}

// =====================================================================
// Persistent kernel v13 = v11 structure, unconfounded:
//   v11's regression was launch_bounds(512,2) VGPR starvation (64), not
//   the structure. v13: (512,1) -> allocator free up to 256 (block-size
//   cap); occupancy unchanged (LDS fixes 1 block/CU, 2 waves/SIMD).
//   Waves 0-3: gates, 32 rows each, full K (LDS B-reads halved:
//   1024->512 b128/CU/step ~ -2.9us of LDS pipe if the model is right).
//   Waves 4-7: FC for h_{t-1} concurrent, fc_w hi+lo PINNED in their
//   registers (removes 128KB/step fc_w L2 stream that v11 ran against
//   gates' h reads). Touch-prefetch 4 threads/slice. Busy-poll.
//   Keeps: pure-bf16 h, W-LDS swizzled tile, block-major h (full-line
//   sc1 stores), flag-array barrier, fence-then-poll+touch tail.
// =====================================================================
__global__ void __launch_bounds__(NTHR, 1)
persist_kernel(const ushort* __restrict__ Whhh, const ushort* __restrict__ Whhl,
               const float* __restrict__ zbuf,
               ushort* __restrict__ hbh, ushort* __restrict__ hbl,
               const ushort* __restrict__ fcwh, const ushort* __restrict__ fcwl,
               const float* __restrict__ fcb, float* __restrict__ out,
               float* __restrict__ out_ns, unsigned* __restrict__ flags,
               int T) {
  (void)hbl;  // lo-plane of h eliminated (v10)
  extern __shared__ char smem[];
  char* WlB = smem + 65536;                           // W lo plane
  float* red = (float*)(smem + 131072);               // [128][RED36]
  float* fred = (float*)(smem + 131072 + BB * RED36 * 4);  // [4][256]

  const int tid = threadIdx.x;
  const int hb = blockIdx.x;      // h-slice (8 cols) = k-block it produces
  const int lane = tid & 63;
  const int w = tid >> 6;         // 0..7; w<4 gates, w>=4 FC
  const int fr = lane & 15;
  const int q = lane >> 4;        // 0..3
  const int fk8 = q * 8;
  const int swz = (fr & 7) << 4;
  const f32x4 fz = {0.f, 0.f, 0.f, 0.f};

  // ---- stage W_hh tile into LDS once (swizzled) ----
  for (int i = tid; i < 32 * 128; i += NTHR) {
    int r = i >> 7;                 // local gate row (= g*8+c)
    int cb = (i & 127) * 16;        // byte within row
    int g = r >> 3, c = r & 7;
    size_t go = ((size_t)(g * HH + hb * 8 + c)) * (HH * 2) + (size_t)cb;
    int lofs = r * 2048 + (cb ^ ((r & 7) << 4));
    *(uint4*)(smem + lofs) = *(const uint4*)((const char*)Whhh + go);
    *(uint4*)(WlB + lofs) = *(const uint4*)((const char*)Whhl + go);
  }

  // ---- per-thread cell state + z preload (2 cells/thread) ----
  const int crow = tid >> 3, ccol = tid & 7;  // rows crow and crow+64
  float creg0 = 0.f, creg1 = 0.f;
  size_t zb0 = (size_t)crow * G4 + hb * 8 + ccol;
  size_t zb1 = (size_t)(crow + 64) * G4 + hb * 8 + ccol;
  float zi0 = zbuf[zb0], zf0 = zbuf[zb0 + HH];
  float zg0 = zbuf[zb0 + 2 * HH], zo0 = zbuf[zb0 + 3 * HH];
  float zi1 = zbuf[zb1], zf1 = zbuf[zb1 + HH];
  float zg1 = zbuf[zb1 + 2 * HH], zo1 = zbuf[zb1 + 3 * HH];

  // ---- FC geometry: block tile = 16 out-rows x 32 out-cols.
  //      FC waves: fw = w-4 = fkh*2 + fwo (fkh = K-half of 512).
  //      fc_w hi+lo pinned in FC-wave registers (branch-local). ----
  const int m0f = (hb >> 4) * 16;
  const int o0 = (hb & 15) * 32;
  const int fw = w - 4;
  const int fwo = fw & 1, fkh = (fw >> 1) & 1;
  s16x8 fbh[16], fbl[16];
  if (w >= 4) {
    size_t base = (size_t)(o0 + fwo * 16 + fr) * HH + (size_t)fkh * 512 + fk8;
#pragma unroll
    for (int j = 0; j < 16; ++j) {
      fbh[j] = *(const s16x8*)&fcwh[base + j * 32];
      fbl[j] = *(const s16x8*)&fcwl[base + j * 32];
    }
  }
  const float fcbv = fcb[o0 + (tid >> 8) * 16 + (tid & 15)];
  __syncthreads();  // W staged

  for (int t = 0; t <= T; ++t) {
    // ================= phase 1: gates (w<4) || FC (w>=4) =================
    if (t > 0) {
      if (w < 4) {
        if (t < T) {
          // gates: rows w*32..w*32+31, full K; per (c,j): 4 B-reads feed
          // 8 MFMAs. Accumulation order == v10 (h bit-identical).
          const ushort* hph = hbh + (size_t)((t - 1) & 3) * (BB * HH);
          const ushort* ha0 =
              hph + (size_t)(w * 32 + fr) * 8 + (size_t)q * (BB * 8);
          const ushort* ha1 = ha0 + 128;  // rows +16
          f32x4 a00 = fz, a01 = fz, a10 = fz, a11 = fz;
          s16x8 p0[2][4], p1[2][4];
#pragma unroll
          for (int j = 0; j < 4; ++j) {
            p0[0][j] = *(const s16x8*)&ha0[(j * 4) * (BB * 8)];
            p1[0][j] = *(const s16x8*)&ha1[(j * 4) * (BB * 8)];
          }
#pragma unroll
          for (int c = 0; c < 8; ++c) {
            if (c < 7) {
#pragma unroll
              for (int j = 0; j < 4; ++j) {
                p0[(c + 1) & 1][j] =
                    *(const s16x8*)&ha0[((c + 1) * 16 + j * 4) * (BB * 8)];
                p1[(c + 1) & 1][j] =
                    *(const s16x8*)&ha1[((c + 1) * 16 + j * 4) * (BB * 8)];
              }
            }
#pragma unroll
            for (int j = 0; j < 4; ++j) {
              int kk = c * 128 + j * 32 + fk8;
              int sw = (kk * 2) ^ swz;
              int ofs0 = fr * 2048 + sw;
              int ofs1 = (16 + fr) * 2048 + sw;
              s16x8 bh0 = *(const s16x8*)(smem + ofs0);
              s16x8 bl0 = *(const s16x8*)(WlB + ofs0);
              s16x8 bh1 = *(const s16x8*)(smem + ofs1);
              s16x8 bl1 = *(const s16x8*)(WlB + ofs1);
              s16x8 ah0 = p0[c & 1][j], ah1 = p1[c & 1][j];
              a00 = mfma_bf16(ah0, bh0, a00);
              a00 = mfma_bf16(ah0, bl0, a00);
              a01 = mfma_bf16(ah0, bh1, a01);
              a01 = mfma_bf16(ah0, bl1, a01);
              a10 = mfma_bf16(ah1, bh0, a10);
              a10 = mfma_bf16(ah1, bl0, a10);
              a11 = mfma_bf16(ah1, bh1, a11);
              a11 = mfma_bf16(ah1, bl1, a11);
            }
          }
          int rr = w * 32 + q * 4;
#pragma unroll
          for (int r = 0; r < 4; ++r) {
            red[(rr + r) * RED36 + fr] = a00[r];
            red[(rr + r) * RED36 + 16 + fr] = a01[r];
            red[(rr + 16 + r) * RED36 + fr] = a10[r];
            red[(rr + 16 + r) * RED36 + 16 + fr] = a11[r];
          }
        }
      } else {
        // FC (concurrent): out[:, t-1, :] partials; fc_w from registers.
        const ushort* hch = hbh + (size_t)((t - 1) & 3) * (BB * HH);
        const ushort* hca = hch + (size_t)(m0f + fr) * 8 +
                            (size_t)(fkh * 64 + q) * (BB * 8);
        f32x4 acc = fz;
#pragma unroll
        for (int j = 0; j < 16; ++j) {
          s16x8 afh = *(const s16x8*)&hca[(j * 4) * (BB * 8)];
          acc = mfma_bf16(afh, fbh[j], acc);
          acc = mfma_bf16(afh, fbl[j], acc);
        }
#pragma unroll
        for (int r = 0; r < 4; ++r)
          fred[fw * 256 + (q * 4 + r) * 16 + fr] = acc[r];
      }
    }
    __syncthreads();
    // ================= phase 2: cell (+h store) and FC-final ============
    if (t < T) {
      float gi0 = zi0, gf0 = zf0, gg0 = zg0, go0 = zo0;
      float gi1 = zi1, gf1 = zf1, gg1 = zg1, go1 = zo1;
      if (t > 0) {
        const float* r0 = red + crow * RED36;
        const float* r1 = red + (crow + 64) * RED36;
        gi0 += r0[ccol];      gi1 += r1[ccol];
        gf0 += r0[8 + ccol];  gf1 += r1[8 + ccol];
        gg0 += r0[16 + ccol]; gg1 += r1[16 + ccol];
        go0 += r0[24 + ccol]; go1 += r1[24 + ccol];
      }
      float iv0 = sigm(gi0), fv0 = sigm(gf0), gv0 = tanhf(gg0), ov0 = sigm(go0);
      float iv1 = sigm(gi1), fv1 = sigm(gf1), gv1 = tanhf(gg1), ov1 = sigm(go1);
      creg0 = fv0 * creg0 + iv0 * gv0;
      creg1 = fv1 * creg1 + iv1 * gv1;
      float hv0 = ov0 * tanhf(creg0);
      float hv1 = ov1 * tanhf(creg1);
      ushort hh0 = f2bf(hv0);
      ushort hh1 = f2bf(hv1);
      size_t hob = (size_t)(t & 3) * (BB * HH) + (size_t)hb * (BB * 8);
      store_short_agent(hbh + hob + tid, hh0);         // row crow
      store_short_agent(hbh + hob + 512 + tid, hh1);   // row crow+64
      if (t == T - 1 && crow == 63) out_ns[hb * 8 + ccol] = hv1;
    }
    if (t > 0) {
      int wo2 = tid >> 8, row = (tid >> 4) & 15, col = tid & 15;
      float s = fcbv + fred[wo2 * 256 + row * 16 + col] +
                fred[(2 + wo2) * 256 + row * 16 + col];
      out[((size_t)(m0f + row) * T + (t - 1)) * OO + o0 + wo2 * 16 + col] = s;
    }
    // ================= phase 3: barrier (post, inv, poll+touch) =========
    if (t < T) {
      __syncthreads();  // drains sc1 h stores (vmcnt(0) before s_barrier)
      if (tid == 0) {
        __hip_atomic_store(&flags[hb * FLAGSTRIDE], (unsigned)(t + 1),
                           __ATOMIC_RELAXED, __HIP_MEMORY_SCOPE_AGENT);
      }
      if (tid < 64) __builtin_amdgcn_fence(__ATOMIC_ACQUIRE, "agent");
      __syncthreads();  // inv complete before touches
      {
        // 4 threads per slice: i = tid>>2, sub = tid&3. All 4 poll the
        // same flag (same line, broadcast); owners touch 8 lines each.
        const int i = tid >> 2, sub = tid & 3;
        unsigned tgt = (unsigned)(t + 1);
        unsigned spins = 0;
        while (__hip_atomic_load(&flags[i * FLAGSTRIDE], __ATOMIC_RELAXED,
                                 __HIP_MEMORY_SCOPE_AGENT) < tgt) {
          if (++spins > 256u) __builtin_amdgcn_s_sleep(1);  // busy first
          if (spins > SPIN_LIMIT) break;  // hang-proof bail
        }
        // owner: one block per XCD per slice (intra-XCD index b>>3);
        // touch slice i (2KB hi) spread across 4 threads (8 lines each)
        if ((i >> 3) == (hb >> 3)) {
          const uint* ph2 =
              (const uint*)(hbh + (size_t)(t & 3) * (BB * HH) + i * (BB * 8));
          unsigned acc2 = 0;
#pragma unroll
          for (int k2 = 0; k2 < 8; ++k2) acc2 += ph2[(sub * 8 + k2) * 16];
          asm volatile("" :: "v"(acc2));  // keep touches live (no DCE)
        }
      }
      __syncthreads();
    }
  }
}

extern "C" void kernel_launch(void* const* d_in, const int* in_sizes, int n_in,
                              void* d_out, int out_size, void* d_ws,
                              size_t ws_size, hipStream_t stream) {
  (void)ws_size;
  // ---- order-agnostic input identification by element count ----
  const float *x = nullptr, *Wih = nullptr, *Whh = nullptr, *fcw = nullptr;
  const float *bih = nullptr, *bhh = nullptr, *fcb = nullptr;
  for (int i = 0; i < n_in; ++i) {
    int s = in_sizes[i];
    const float* p = (const float*)d_in[i];
    if (s == BB * EE && !x) x = p;
    else if (s == G4 * EE && !Wih) Wih = p;
    else if (s == G4 * HH && !Whh) Whh = p;
    else if (s == OO * HH && !fcw) fcw = p;
    else if (s == G4 && !bih) bih = p;
    else if (s == G4 && !bhh) bhh = p;  // bias order irrelevant (summed)
    else if (s == OO && !fcb) fcb = p;
  }
  if (!x || !Wih || !Whh || !fcw || !bih || !bhh || !fcb) return;

  // ---- runtime T from out_size ----
  int T = 0;
  if (out_size >= BB * OO && (out_size - HH) % (BB * OO) == 0 &&
      (out_size - HH) / (BB * OO) >= 1) {
    T = (out_size - HH) / (BB * OO);
  } else if (out_size % (BB * OO) == 0) {
    T = out_size / (BB * OO);
  }
  if (T < 1 || T > 16384) return;

  float* out = (float*)d_out;
  float* out_ns = out + (size_t)BB * T * OO;

  // ---- ws layout (hbl slot kept for layout stability; unused) ----
  ushort* xh = (ushort*)d_ws;
  ushort* xl = xh + (size_t)BB * EE;
  ushort* Wihh = xl + (size_t)BB * EE;
  ushort* Wihl = Wihh + (size_t)G4 * EE;
  ushort* Whhh = Wihl + (size_t)G4 * EE;
  ushort* Whhl = Whhh + (size_t)G4 * HH;
  ushort* fcwh = Whhl + (size_t)G4 * HH;
  ushort* fcwl = fcwh + (size_t)OO * HH;
  ushort* hbh = fcwl + (size_t)OO * HH;               // 4 x B x H (4-deep)
  ushort* hbl = hbh + (size_t)4 * BB * HH;            // unused
  float* zbuf = (float*)(hbl + (size_t)4 * BB * HH);  // 128*4096 f32
  unsigned* flags = (unsigned*)(zbuf + (size_t)BB * G4);  // 128 x 16 uints

  {
    long total = (long)BB * EE + (long)G4 * EE + (long)G4 * HH + (long)OO * HH;
    int cblocks = (int)(total / 4 / 256);  // exact
    hipLaunchKernelGGL(convert_split, dim3(cblocks), dim3(256), 0, stream, x,
                       Wih, Whh, fcw, xh, xl, Wihh, Wihl, Whhh, Whhl, fcwh,
                       fcwl, flags);
  }
  hipLaunchKernelGGL(z_split, dim3(256), dim3(256), 0, stream, xh, xl, Wihh,
                     Wihl, bih, bhh, zbuf);

  static int attr_set = 0;
  if (!attr_set) {
    (void)hipFuncSetAttribute((const void*)persist_kernel,
                              hipFuncAttributeMaxDynamicSharedMemorySize,
                              SMEM_BYTES);
    attr_set = 1;
  }
  // PLAIN launch (graph-capture-safe). 128 blocks, 1 block/CU on 256 CUs
  // -> co-residency with 2x headroom; spin bail guards the residual risk.
  hipLaunchKernelGGL(persist_kernel, dim3(NBLKP), dim3(NTHR), SMEM_BYTES,
                     stream, Whhh, Whhl, zbuf, hbh, hbl, fcwh, fcwl, fcb, out,
                     out_ns, flags, T);
}

// Round 14
// 1588.220 us; speedup vs baseline: 1.6603x; 1.6603x over previous
//
#include <hip/hip_runtime.h>
#include <cstdint>
#include <cstddef>

#define BB 128   // batch
#define EE 512   // input dim
#define HH 1024  // hidden
#define G4 4096
#define OO 512   // output dim
#define NBLKP 128    // persistent grid: 128 blocks (residency ceiling; 256 failed r9)
#define NTHR 512     // 8 waves, symmetric (specialization regressed: v13)
#define RED36 36     // reduce-buffer row stride (floats)
#define SMEM_BYTES (65536 + BB * RED36 * 4)  // W hi only (64KB) + red
#define SPIN_LIMIT (1u << 16)  // bounded spin: deadlock -> wrong answer, not hang
#define FLAGSTRIDE 16          // flags spaced 64B apart

typedef float f32x4 __attribute__((ext_vector_type(4)));
typedef short s16x8 __attribute__((ext_vector_type(8)));
typedef __bf16 b16x8 __attribute__((ext_vector_type(8)));

// ---- mfma dispatch: tolerate either short8- or bf16x8-typed builtin ----
template <typename V>
__device__ __forceinline__ auto mfma_try(V a, V b, f32x4 c, int)
    -> decltype(__builtin_amdgcn_mfma_f32_16x16x32_bf16(a, b, c, 0, 0, 0)) {
  return __builtin_amdgcn_mfma_f32_16x16x32_bf16(a, b, c, 0, 0, 0);
}
template <typename V>
__device__ __forceinline__ f32x4 mfma_try(V a, V b, f32x4 c, long) {
  b16x8 ab = __builtin_bit_cast(b16x8, a);
  b16x8 bb = __builtin_bit_cast(b16x8, b);
  return __builtin_amdgcn_mfma_f32_16x16x32_bf16(ab, bb, c, 0, 0, 0);
}
__device__ __forceinline__ f32x4 mfma_bf16(s16x8 a, s16x8 b, f32x4 c) {
  return mfma_try(a, b, c, 0);
}

__device__ __forceinline__ float bf2f(ushort s) {
  unsigned int u = ((unsigned int)s) << 16;
  return __builtin_bit_cast(float, u);
}
__device__ __forceinline__ ushort f2bf(float f) {
  unsigned int u = __builtin_bit_cast(unsigned int, f);
  unsigned int r = (u + 0x7fffu + ((u >> 16) & 1u)) >> 16;
  return (ushort)r;
}
__device__ __forceinline__ float sigm(float x) {
  return 1.0f / (1.0f + __expf(-x));
}
// write-through agent-scope 16-bit store (block-major h => full 64B lines)
__device__ __forceinline__ void store_short_agent(ushort* p, ushort v) {
  asm volatile("global_store_short %0, %1, off sc1"
               :: "v"(p), "v"((unsigned)v) : "memory");
}

// ======== fp32 -> split bf16 (hi+lo) for x, W_ih, W_hh, fc_w ============
__global__ void __launch_bounds__(256)
convert_split(const float* __restrict__ x, const float* __restrict__ Wih,
              const float* __restrict__ Whh, const float* __restrict__ fcw,
              ushort* __restrict__ xh, ushort* __restrict__ xl,
              ushort* __restrict__ Wihh, ushort* __restrict__ Wihl,
              ushort* __restrict__ Whhh, ushort* __restrict__ Whhl,
              ushort* __restrict__ fcwh, ushort* __restrict__ fcwl,
              unsigned* __restrict__ flags) {
  if (blockIdx.x == 0) {
    for (int j = threadIdx.x; j < NBLKP * FLAGSTRIDE; j += 256) flags[j] = 0u;
  }
  const long n0 = (long)BB * EE;
  const long n1 = n0 + (long)G4 * EE;
  const long n2 = n1 + (long)G4 * HH;
  long i = ((long)blockIdx.x * 256 + threadIdx.x) * 4;
  const float* src;
  ushort *dh, *dl;
  long off;
  if (i < n0) {
    src = x; dh = xh; dl = xl; off = i;
  } else if (i < n1) {
    src = Wih; dh = Wihh; dl = Wihl; off = i - n0;
  } else if (i < n2) {
    src = Whh; dh = Whhh; dl = Whhl; off = i - n1;
  } else {
    src = fcw; dh = fcwh; dl = fcwl; off = i - n2;
  }
  float4 v = *(const float4*)&src[off];
  ushort4 h;
  h.x = f2bf(v.x); h.y = f2bf(v.y); h.z = f2bf(v.z); h.w = f2bf(v.w);
  *(ushort4*)&dh[off] = h;
  ushort4 l;
  l.x = f2bf(v.x - bf2f(h.x));
  l.y = f2bf(v.y - bf2f(h.y));
  l.z = f2bf(v.z - bf2f(h.z));
  l.w = f2bf(v.w - bf2f(h.w));
  *(ushort4*)&dl[off] = l;
}

// ========== z = x @ W_ih^T + (b_ih+b_hh) -> zbuf fp32 [B][4H] ===========
__global__ void __launch_bounds__(256)
z_split(const ushort* __restrict__ xh, const ushort* __restrict__ xl,
        const ushort* __restrict__ Wihh, const ushort* __restrict__ Wihl,
        const float* __restrict__ bih, const float* __restrict__ bhh,
        float* __restrict__ zbuf) {
  __shared__ alignas(16) ushort Ah[64][72];
  __shared__ alignas(16) ushort Al[64][72];
  __shared__ alignas(16) ushort Bh[32][72];
  __shared__ alignas(16) ushort Bl[32][72];
  const int tid = threadIdx.x, bid = blockIdx.x;
  const int m0 = (bid >> 7) * 64;
  const int hbase = (bid & 127) * 8;
  const int lane = tid & 63, wave = tid >> 6;
  const int wm = wave & 1, wn = wave >> 1;
  const int fr_row = lane & 15, fr_k = (lane >> 4) * 8;
  const f32x4 fz = {0.f, 0.f, 0.f, 0.f};

  f32x4 a0 = fz, a1 = fz;
  for (int kt = 0; kt < EE / 64; ++kt) {
    for (int i = 0; i < 2; ++i) {
      int idx = tid + i * 256;
      int r = idx >> 3, c8 = (idx & 7) * 8;
      int go = (m0 + r) * EE + kt * 64 + c8;
      *(uint4*)&Ah[r][c8] = *(const uint4*)&xh[go];
      *(uint4*)&Al[r][c8] = *(const uint4*)&xl[go];
    }
    {
      int r = tid >> 3, c8 = (tid & 7) * 8;
      int wrow = (r >> 3) * HH + hbase + (r & 7);
      int go = wrow * EE + kt * 64 + c8;
      *(uint4*)&Bh[r][c8] = *(const uint4*)&Wihh[go];
      *(uint4*)&Bl[r][c8] = *(const uint4*)&Wihl[go];
    }
    __syncthreads();
    for (int kc = 0; kc < 2; ++kc) {
      int ko = kc * 32 + fr_k;
      s16x8 bh = *(const s16x8*)&Bh[wn * 16 + fr_row][ko];
      s16x8 bl = *(const s16x8*)&Bl[wn * 16 + fr_row][ko];
      s16x8 f0h = *(const s16x8*)&Ah[wm * 32 + fr_row][ko];
      s16x8 f0l = *(const s16x8*)&Al[wm * 32 + fr_row][ko];
      s16x8 f1h = *(const s16x8*)&Ah[wm * 32 + 16 + fr_row][ko];
      s16x8 f1l = *(const s16x8*)&Al[wm * 32 + 16 + fr_row][ko];
      a0 = mfma_bf16(f0h, bh, a0);
      a0 = mfma_bf16(f0l, bh, a0);
      a0 = mfma_bf16(f0h, bl, a0);
      a1 = mfma_bf16(f1h, bh, a1);
      a1 = mfma_bf16(f1l, bh, a1);
      a1 = mfma_bf16(f1h, bl, a1);
    }
    __syncthreads();
  }
  int jcol = wn * 16 + fr_row;
  int gc = (jcol >> 3) * HH + hbase + (jcol & 7);
  float bias = bih[gc] + bhh[gc];
  int rbase = wm * 32 + (lane >> 4) * 4;
#pragma unroll
  for (int r = 0; r < 4; ++r) {
    zbuf[(size_t)(m0 + rbase + r) * G4 + gc] = a0[r] + bias;
    zbuf[(size_t)(m0 + rbase + 16 + r) * G4 + gc] = a1[r] + bias;
  }
}

// =====================================================================
// Persistent kernel v14 = v12 (best symmetric structure) + W-lo dropped
//   from gates. v13 lesson: specialization exposes latency (1 gates
//   wave/SIMD); only symmetric 8-wave works. v14 halves the LDS stream
//   the unconfounded way: gates = bf16(h) x bf16(W_hi) only ->
//   512 ds_read_b128/CU/step (was 1024), 512 MFMAs/block (was 1024),
//   W LDS tile 64 KB (was 128). Error budget: W-lo dot-error ~6e-4/step
//   pre-activation, same scale as v10's h-lo drop which moved absmax by
//   ZERO; threshold margin 6x. FC keeps fc_w hi+lo (register-pinned,
//   runs in slack - no cost). Canaries: absmax <= 0.0124, VGPR >= 100.
//   Keeps: pure-bf16 h, block-major h (full-line sc1), flag barrier,
//   fence-then-poll+touch, 4-deep ring + XCD stagger, busy-poll.
// =====================================================================
__global__ void __launch_bounds__(NTHR, 1)
persist_kernel(const ushort* __restrict__ Whhh, const ushort* __restrict__ Whhl,
               const float* __restrict__ zbuf,
               ushort* __restrict__ hbh, ushort* __restrict__ hbl,
               const ushort* __restrict__ fcwh, const ushort* __restrict__ fcwl,
               const float* __restrict__ fcb, float* __restrict__ out,
               float* __restrict__ out_ns, unsigned* __restrict__ flags,
               int T) {
  (void)hbl;   // h lo-plane eliminated (v10)
  (void)Whhl;  // W lo-plane eliminated from gates (v14)
  extern __shared__ char smem[];
  float* red = (float*)(smem + 65536);   // [128][RED36] f32 (also FC 8x256)

  const int tid = threadIdx.x;
  const int hb = blockIdx.x;      // h-slice (8 cols) = k-block it produces
  const int lane = tid & 63;
  const int w = tid >> 6;         // 0..7 (= gates m-tile)
  const int fr = lane & 15;
  const int fk8 = (lane >> 4) * 8;
  const int swz = (fr & 7) << 4;
  const int xcd = hb & 7;         // XCD id under round-robin dispatch
  const f32x4 fz = {0.f, 0.f, 0.f, 0.f};

  // ---- stage W_hh hi tile into LDS once (swizzled) ----
  for (int i = tid; i < 32 * 128; i += NTHR) {
    int r = i >> 7;                 // local gate row (= g*8+c)
    int cb = (i & 127) * 16;        // byte within row
    int g = r >> 3, c = r & 7;
    size_t go = ((size_t)(g * HH + hb * 8 + c)) * (HH * 2) + (size_t)cb;
    int lofs = r * 2048 + (cb ^ ((r & 7) << 4));
    *(uint4*)(smem + lofs) = *(const uint4*)((const char*)Whhh + go);
  }

  // ---- per-thread cell state + z preload (2 cells/thread) ----
  const int crow = tid >> 3, ccol = tid & 7;  // rows crow and crow+64
  float creg0 = 0.f, creg1 = 0.f;
  size_t zb0 = (size_t)crow * G4 + hb * 8 + ccol;
  size_t zb1 = (size_t)(crow + 64) * G4 + hb * 8 + ccol;
  float zi0 = zbuf[zb0], zf0 = zbuf[zb0 + HH];
  float zg0 = zbuf[zb0 + 2 * HH], zo0 = zbuf[zb0 + 3 * HH];
  float zi1 = zbuf[zb1], zf1 = zbuf[zb1 + HH];
  float zg1 = zbuf[zb1 + 2 * HH], zo1 = zbuf[zb1 + 3 * HH];

  // ---- FC constants: block = 16 out-rows x 32 out-cols; 8 waves =
  //      2 col-halves x 4-way K-split(256). fc_w hi+lo pinned in regs.
  const int m0f = (hb >> 4) * 16;
  const int o0 = (hb & 15) * 32;
  const int wo = w & 1, wkf = w >> 1;
  s16x8 fbh[8], fbl[8];
  {
    size_t base = (size_t)(o0 + wo * 16 + fr) * HH + wkf * 256 + fk8;
#pragma unroll
    for (int j = 0; j < 8; ++j) {
      fbh[j] = *(const s16x8*)&fcwh[base + j * 32];
      fbl[j] = *(const s16x8*)&fcwl[base + j * 32];
    }
  }
  const float fcbv = fcb[o0 + (tid >> 8) * 16 + (tid & 15)];
  __syncthreads();  // W staged

  for (int t = 0; t <= T; ++t) {
    if (t < T) {
      if (t > 0) {
        // ---- gates: bf16(h_{t-1}) @ bf16(Whh_hi)^T, full K per wave;
        //      4-deep chunk ring, XCD-staggered chunk order ----
        const ushort* hph = hbh + (size_t)((t - 1) & 3) * (BB * HH);
        const ushort* ha =
            hph + (size_t)(w * 16 + fr) * 8 + (size_t)(lane >> 4) * (BB * 8);
        f32x4 a0 = fz, a1 = fz;
        s16x8 ph[4][4];
#pragma unroll
        for (int c0 = 0; c0 < 3; ++c0) {
          int pc = (c0 + xcd) & 7;
#pragma unroll
          for (int j = 0; j < 4; ++j)
            ph[c0][j] = *(const s16x8*)&ha[(pc * 16 + j * 4) * (BB * 8)];
        }
#pragma unroll
        for (int ci = 0; ci < 8; ++ci) {
          int pc = (ci + xcd) & 7;
          if (ci + 3 < 8) {
            int pn = (ci + 3 + xcd) & 7;
#pragma unroll
            for (int j = 0; j < 4; ++j)
              ph[(ci + 3) & 3][j] =
                  *(const s16x8*)&ha[(pn * 16 + j * 4) * (BB * 8)];
          }
#pragma unroll
          for (int j = 0; j < 4; ++j) {
            int kk = pc * 128 + j * 32 + fk8;
            int sw = (kk * 2) ^ swz;
            int ofs0 = fr * 2048 + sw;
            int ofs1 = (16 + fr) * 2048 + sw;
            s16x8 bh0 = *(const s16x8*)(smem + ofs0);
            s16x8 bh1 = *(const s16x8*)(smem + ofs1);
            s16x8 ah = ph[ci & 3][j];
            a0 = mfma_bf16(ah, bh0, a0);
            a1 = mfma_bf16(ah, bh1, a1);
          }
        }
        // ---- scatter complete gate sums ----
        int rrow = w * 16 + (lane >> 4) * 4;
#pragma unroll
        for (int r = 0; r < 4; ++r) {
          red[(rrow + r) * RED36 + fr] = a0[r];
          red[(rrow + r) * RED36 + 16 + fr] = a1[r];
        }
        __syncthreads();
      }
      // ---- LSTM cell (fp32, c in regs); h_t stored block-major bf16 --
      {
        float gi0 = zi0, gf0 = zf0, gg0 = zg0, go0 = zo0;
        float gi1 = zi1, gf1 = zf1, gg1 = zg1, go1 = zo1;
        if (t > 0) {
          const float* r0 = red + crow * RED36;
          const float* r1 = red + (crow + 64) * RED36;
          gi0 += r0[ccol];      gi1 += r1[ccol];
          gf0 += r0[8 + ccol];  gf1 += r1[8 + ccol];
          gg0 += r0[16 + ccol]; gg1 += r1[16 + ccol];
          go0 += r0[24 + ccol]; go1 += r1[24 + ccol];
        }
        float iv0 = sigm(gi0), fv0 = sigm(gf0), gv0 = tanhf(gg0), ov0 = sigm(go0);
        float iv1 = sigm(gi1), fv1 = sigm(gf1), gv1 = tanhf(gg1), ov1 = sigm(go1);
        creg0 = fv0 * creg0 + iv0 * gv0;
        creg1 = fv1 * creg1 + iv1 * gv1;
        float hv0 = ov0 * tanhf(creg0);
        float hv1 = ov1 * tanhf(creg1);
        ushort hh0 = f2bf(hv0);
        ushort hh1 = f2bf(hv1);
        size_t hob = (size_t)(t & 3) * (BB * HH) + (size_t)hb * (BB * 8);
        store_short_agent(hbh + hob + tid, hh0);         // row crow
        store_short_agent(hbh + hob + 512 + tid, hh1);   // row crow+64
        if (t == T - 1 && crow == 63) out_ns[hb * 8 + ccol] = hv1;
      }
      // ---- barrier arrive: syncthreads' vmcnt(0) drains the sc1
      //      stores (full-line write-through, globally visible); flag.
      __syncthreads();
      if (tid == 0) {
        __hip_atomic_store(&flags[hb * FLAGSTRIDE], (unsigned)(t + 1),
                           __ATOMIC_RELAXED, __HIP_MEMORY_SCOPE_AGENT);
      }
    }
    // ---- delayed FC for h_{t-1}: overlapped with barrier slack ----
    if (t > 0) {
      const ushort* hch = hbh + (size_t)((t - 1) & 3) * (BB * HH);
      const ushort* hca =
          hch + (size_t)(m0f + fr) * 8 + (size_t)(lane >> 4) * (BB * 8);
      f32x4 acc = fz;
#pragma unroll
      for (int j = 0; j < 8; ++j) {
        s16x8 afh = *(const s16x8*)&hca[(wkf * 32 + j * 4) * (BB * 8)];
        acc = mfma_bf16(afh, fbh[j], acc);
        acc = mfma_bf16(afh, fbl[j], acc);
      }
      int rb = (lane >> 4) * 4;
      float* rp = red + (wkf * 2 + wo) * 256;
#pragma unroll
      for (int r = 0; r < 4; ++r) rp[(rb + r) * 16 + fr] = acc[r];
      __syncthreads();
      {
        int wo2 = tid >> 8, row = (tid >> 4) & 15, col = tid & 15;
        float s = fcbv;
#pragma unroll
        for (int k = 0; k < 4; ++k)
          s += red[(k * 2 + wo2) * 256 + row * 16 + col];
        out[((size_t)(m0f + row) * T + (t - 1)) * OO + o0 + wo2 * 16 + col] = s;
      }
    }
    // ---- barrier wait: inv FIRST, then poll + touch-prefetch (hi only)
    if (t < T) {
      if (tid < 64) __builtin_amdgcn_fence(__ATOMIC_ACQUIRE, "agent");
      __syncthreads();  // inv complete before touches
      if (tid < NBLKP) {
        const int i = tid;  // poller i watches block i's flag
        unsigned tgt = (unsigned)(t + 1);
        unsigned spins = 0;
        while (__hip_atomic_load(&flags[i * FLAGSTRIDE], __ATOMIC_RELAXED,
                                 __HIP_MEMORY_SCOPE_AGENT) < tgt) {
          if (++spins > 256u) __builtin_amdgcn_s_sleep(1);  // busy first
          if (spins > SPIN_LIMIT) break;  // hang-proof bail
        }
        // owner: one block per XCD per slice (intra-XCD index b>>3);
        // touch slice i (2KB hi) at 64B stride -> fills L2 lines
        if ((i >> 3) == (hb >> 3)) {
          const uint* ph2 =
              (const uint*)(hbh + (size_t)(t & 3) * (BB * HH) + i * (BB * 8));
          unsigned acc2 = 0;
#pragma unroll
          for (int k2 = 0; k2 < 32; ++k2) acc2 += ph2[k2 * 16];
          asm volatile("" :: "v"(acc2));  // keep touches live (no DCE)
        }
      }
      __syncthreads();
    }
  }
}

extern "C" void kernel_launch(void* const* d_in, const int* in_sizes, int n_in,
                              void* d_out, int out_size, void* d_ws,
                              size_t ws_size, hipStream_t stream) {
  (void)ws_size;
  // ---- order-agnostic input identification by element count ----
  const float *x = nullptr, *Wih = nullptr, *Whh = nullptr, *fcw = nullptr;
  const float *bih = nullptr, *bhh = nullptr, *fcb = nullptr;
  for (int i = 0; i < n_in; ++i) {
    int s = in_sizes[i];
    const float* p = (const float*)d_in[i];
    if (s == BB * EE && !x) x = p;
    else if (s == G4 * EE && !Wih) Wih = p;
    else if (s == G4 * HH && !Whh) Whh = p;
    else if (s == OO * HH && !fcw) fcw = p;
    else if (s == G4 && !bih) bih = p;
    else if (s == G4 && !bhh) bhh = p;  // bias order irrelevant (summed)
    else if (s == OO && !fcb) fcb = p;
  }
  if (!x || !Wih || !Whh || !fcw || !bih || !bhh || !fcb) return;

  // ---- runtime T from out_size ----
  int T = 0;
  if (out_size >= BB * OO && (out_size - HH) % (BB * OO) == 0 &&
      (out_size - HH) / (BB * OO) >= 1) {
    T = (out_size - HH) / (BB * OO);
  } else if (out_size % (BB * OO) == 0) {
    T = out_size / (BB * OO);
  }
  if (T < 1 || T > 16384) return;

  float* out = (float*)d_out;
  float* out_ns = out + (size_t)BB * T * OO;

  // ---- ws layout (hbl/Whhl slots kept for layout stability) ----
  ushort* xh = (ushort*)d_ws;
  ushort* xl = xh + (size_t)BB * EE;
  ushort* Wihh = xl + (size_t)BB * EE;
  ushort* Wihl = Wihh + (size_t)G4 * EE;
  ushort* Whhh = Wihl + (size_t)G4 * EE;
  ushort* Whhl = Whhh + (size_t)G4 * HH;
  ushort* fcwh = Whhl + (size_t)G4 * HH;
  ushort* fcwl = fcwh + (size_t)OO * HH;
  ushort* hbh = fcwl + (size_t)OO * HH;               // 4 x B x H (4-deep)
  ushort* hbl = hbh + (size_t)4 * BB * HH;            // unused in v14
  float* zbuf = (float*)(hbl + (size_t)4 * BB * HH);  // 128*4096 f32
  unsigned* flags = (unsigned*)(zbuf + (size_t)BB * G4);  // 128 x 16 uints

  {
    long total = (long)BB * EE + (long)G4 * EE + (long)G4 * HH + (long)OO * HH;
    int cblocks = (int)(total / 4 / 256);  // exact
    hipLaunchKernelGGL(convert_split, dim3(cblocks), dim3(256), 0, stream, x,
                       Wih, Whh, fcw, xh, xl, Wihh, Wihl, Whhh, Whhl, fcwh,
                       fcwl, flags);
  }
  hipLaunchKernelGGL(z_split, dim3(256), dim3(256), 0, stream, xh, xl, Wihh,
                     Wihl, bih, bhh, zbuf);

  static int attr_set = 0;
  if (!attr_set) {
    (void)hipFuncSetAttribute((const void*)persist_kernel,
                              hipFuncAttributeMaxDynamicSharedMemorySize,
                              SMEM_BYTES);
    attr_set = 1;
  }
  // PLAIN launch (graph-capture-safe). 128 blocks, 1 block/CU on 256 CUs
  // -> co-residency with 2x headroom; spin bail guards the residual risk.
  hipLaunchKernelGGL(persist_kernel, dim3(NBLKP), dim3(NTHR), SMEM_BYTES,
                     stream, Whhh, Whhl, zbuf, hbh, hbl, fcwh, fcwl, fcb, out,
                     out_ns, flags, T);
}